// Round 8
// baseline (37.962 us; speedup 1.0000x reference)
//
#include <hip/hip_runtime.h>
#include <hip/hip_bf16.h>
#include <math.h>

#define NPTS   262144
#define UNITS  256
#define STR    19          // rect row stride used inside prep1 power-build
#define NCO    361         // 19*19 rect slots per (j,net) build
#define LSTR   20          // padded output row stride (float4-friendly)
#define OFF_PU 0           // rows 0..16  -> 17*20 = 340
#define OFF_LU 340         // rows 0..18  -> 19*20 = 380
#define OFF_PV 720
#define OFF_LV 1060
#define CFTOT  1440        // total padded coefficient floats
#define P1BLK  128         // prep1 blocks (4 waves each -> 512 (j,net) tasks)
#define MBLK   1024        // main blocks
#define MTPB   256

// ---------------------------------------------------------------------------
// prep1: one wave per (unit j, net). Builds the unit's contribution to the
// global bivariate polynomials in centered coords X=x-0.5, Y=y-0.5:
//   t(X,Y) = beta*((X-ax)^2 + (Y-ay)^2)      (quadratic)
//   w*exp(-t)          ~ sum_m cP[m] * t^m   (deg-8 Taylor@1, |err|<=5.2e-6)
//   w*phi*(4b^2r2-4b)  = 4wb*(t-1)*exp(-t) ~ sum_m cL[m] * t^m
// ---------------------------------------------------------------------------
__global__ __launch_bounds__(256) void rbf_prep1(
    const float* __restrict__ mu_u, const float* __restrict__ beta_u,
    const float* __restrict__ W_u,
    const float* __restrict__ mu_v, const float* __restrict__ beta_v,
    const float* __restrict__ W_v,
    float* __restrict__ partial,   // [P1BLK][CFTOT]
    int* __restrict__ flagBlk)     // [P1BLK]
{
    const int tid  = threadIdx.x;
    const int bid  = blockIdx.x;
    const int w    = tid >> 6;          // wave 0..3
    const int lane = tid & 63;
    const int id   = bid * 4 + w;       // 0..511
    const int j    = id >> 1;
    const int net  = id & 1;

    __shared__ float pwA[4][NCO];
    __shared__ float pwB[4][NCO];
    __shared__ int   sflag[4];

    const float* mu = net ? mu_v   : mu_u;
    const float* be = net ? beta_v : beta_u;
    const float* W  = net ? W_v    : W_u;
    const float mx  = mu[j], my = mu[UNITS + j];
    const float b   = be[j], wgt = W[j];

    // validity of deg-8 approx over safety box [-0.05,1.05]^2
    const float xlo = -0.05f, xhi = 1.05f;
    const float dxl = xlo - mx, dxh = xhi - mx;
    const float dyl = xlo - my, dyh = xhi - my;
    const float dx2max = fmaxf(dxl*dxl, dxh*dxh);
    const float dy2max = fmaxf(dyl*dyl, dyh*dyh);
    const float dx2min = (dxl <= 0.f && dxh >= 0.f) ? 0.f : fminf(dxl*dxl, dxh*dxh);
    const float dy2min = (dyl <= 0.f && dyh >= 0.f) ? 0.f : fminf(dyl*dyl, dyh*dyh);
    const float t1 = b * (dx2min + dy2min);
    const float t2 = b * (dx2max + dy2max);
    const float tlo = fminf(t1, t2), thi = fmaxf(t1, t2);
    const int bad = !(thi <= 2.2f && tlo >= -0.2f);
    if (lane == 0) sflag[w] = bad;

    // quadratic t(X,Y)
    const float ax = mx - 0.5f, ay = my - 0.5f;
    const float qXX = b, qYY = b;
    const float qX = -2.f*b*ax, qY = -2.f*b*ay;
    const float q0 = b*(ax*ax + ay*ay);

    // monomial coeffs of deg-8 Taylor@1 of e^-t
    const float bb[10] = { 0.9999988846f, -0.9999897571f, 0.4999582306f,
                           -0.1665676867f, 0.0415142033f, -0.0081750986f,
                           0.0012773592f, -0.000145983906f, 9.12498118e-06f, 0.f };
    const float fourwb = 4.f * wgt * b;
    float cP[10], cL[10];
    #pragma unroll
    for (int m = 0; m < 10; ++m) {
        cP[m] = wgt * bb[m];
        cL[m] = fourwb * ((m ? bb[m-1] : 0.f) - bb[m]);
    }

    // lane-owned slots c = lane + 64r
    int   cidx[6], gi[6], gm[6];
    float accP[6], accL[6];
    #pragma unroll
    for (int r = 0; r < 6; ++r) {
        const int c = lane + 64*r;
        cidx[r] = c;
        const int ii = c / STR;
        gi[r] = ii;
        gm[r] = c - STR*ii;
        accP[r] = (c == 0) ? cP[0] : 0.f;
        accL[r] = (c == 0) ? cL[0] : 0.f;
        float v = 0.f;
        if (c == 0)     v = q0;
        if (c == 1)     v = qY;
        if (c == 2)     v = qYY;
        if (c == STR)   v = qX;
        if (c == 2*STR) v = qXX;
        if (c < NCO) { pwA[w][c] = v; pwB[w][c] = 0.f; }
    }
    __threadfence_block();

    float* A = &pwA[w][0];
    float* B = &pwB[w][0];
    #pragma unroll
    for (int m = 1; m <= 9; ++m) {
        #pragma unroll
        for (int r = 0; r < 6; ++r) {
            if (cidx[r] < NCO) {
                const float p = A[cidx[r]];
                accP[r] = fmaf(cP[m], p, accP[r]);
                accL[r] = fmaf(cL[m], p, accL[r]);
            }
        }
        if (m < 9) {
            #pragma unroll
            for (int r = 0; r < 6; ++r) {
                const int c = cidx[r];
                if (c < NCO) {
                    float acc = q0 * A[c];
                    if (gm[r] >= 1) acc = fmaf(qY,  A[c-1],     acc);
                    if (gm[r] >= 2) acc = fmaf(qYY, A[c-2],     acc);
                    if (gi[r] >= 1) acc = fmaf(qX,  A[c-STR],   acc);
                    if (gi[r] >= 2) acc = fmaf(qXX, A[c-2*STR], acc);
                    B[c] = acc;
                }
            }
            float* T = A; A = B; B = T;
            __threadfence_block();
        }
    }

    __syncthreads();
    #pragma unroll
    for (int r = 0; r < 6; ++r) {
        const int c = cidx[r];
        if (c < NCO) { pwA[w][c] = accP[r]; pwB[w][c] = accL[r]; }
    }
    __syncthreads();
    // write ALL 361 rect slots (strided loop — previous version only wrote
    // tid<256!) into the padded stride-20 output layout.
    {
        float* dst = partial + bid * CFTOT;
        for (int c = tid; c < NCO; c += 256) {
            const int i = c / STR;
            const int m = c - STR * i;
            const float pu = pwA[0][c] + pwA[2][c];
            const float lu = pwB[0][c] + pwB[2][c];
            const float pv = pwA[1][c] + pwA[3][c];
            const float lv = pwB[1][c] + pwB[3][c];
            if (i <= 16) {
                dst[OFF_PU + i*LSTR + m] = pu;
                dst[OFF_PV + i*LSTR + m] = pv;
            }
            dst[OFF_LU + i*LSTR + m] = lu;
            dst[OFF_LV + i*LSTR + m] = lv;
        }
    }
    if (tid == 0)
        flagBlk[bid] = sflag[0] | sflag[1] | sflag[2] | sflag[3];
}

// ---------------------------------------------------------------------------
// prep2: fold 128 block-partials into the final coefficient table + flag.
// (pad slots fold poison ~ -3e-13 values; they are never read by eval.)
// ---------------------------------------------------------------------------
__global__ __launch_bounds__(256) void rbf_prep2(
    const float* __restrict__ partial, const int* __restrict__ flagBlk,
    float* __restrict__ coefF, int* __restrict__ flagAll)
{
    const int c = blockIdx.x * 256 + threadIdx.x;
    if (c < CFTOT) {
        float s = 0.f;
        #pragma unroll 8
        for (int p = 0; p < P1BLK; ++p)
            s += partial[p * CFTOT + c];
        coefF[c] = s;
    }
    if (c == CFTOT) {
        int f = 0;
        for (int p = 0; p < P1BLK; ++p) f |= flagBlk[p];
        *flagAll = f;
    }
}

// Horner eval of a padded (stride-20) bivariate poly of total degree D,
// reading coefficients from LDS (same-address broadcast, conflict-free).
template<int D>
__device__ __forceinline__ float eval_poly_lds(const float* C, float X, float Y)
{
    float h = 0.f;
    #pragma unroll
    for (int ii = 0; ii <= D; ++ii) {
        const int i = D - ii;
        float r = C[i*LSTR + (D-i)];
        #pragma unroll
        for (int m = D-i-1; m >= 0; --m)
            r = fmaf(r, Y, C[i*LSTR + m]);
        h = fmaf(h, X, r);
    }
    return h;
}

__global__ __launch_bounds__(MTPB) void rbf_main(
    const float* __restrict__ gx, const float* __restrict__ gy,
    const float* __restrict__ gu, const float* __restrict__ gv,
    const float* __restrict__ gdu, const float* __restrict__ gdv,
    const float* __restrict__ coefF, const int* __restrict__ flagAll,
    const float* __restrict__ mu_u, const float* __restrict__ beta_u,
    const float* __restrict__ W_u,
    const float* __restrict__ mu_v, const float* __restrict__ beta_v,
    const float* __restrict__ W_v,
    const float* __restrict__ p_d, const float* __restrict__ p_a,
    const float* __restrict__ p_b, const float* __restrict__ p_um,
    const float* __restrict__ p_vm, const float* __restrict__ p_us,
    const float* __restrict__ p_vs,
    float* __restrict__ part)
{
    const int tid = threadIdx.x;
    const int bid = blockIdx.x;
    const int i   = bid * MTPB + tid;

    __shared__ __align__(16) float sco[CFTOT];   // 5.76 KB coef table
    {
        const float4* src4 = (const float4*)coefF;
        float4* dst4 = (float4*)sco;
        for (int k = tid; k < CFTOT/4; k += MTPB)
            dst4[k] = src4[k];
    }
    __syncthreads();

    const float x = gx[i], y = gy[i];
    // wave-uniform path select
    const int bad = __builtin_amdgcn_readfirstlane(*flagAll);
    const bool inBox = (x >= -0.05f) && (x <= 1.05f) &&
                       (y >= -0.05f) && (y <= 1.05f);
    const bool allIn = __all(inBox);

    float up, vp, lu, lv;
    if (!bad && allIn) {
        const float X = x - 0.5f, Y = y - 0.5f;
        up = eval_poly_lds<16>(sco + OFF_PU, X, Y);
        lu = eval_poly_lds<18>(sco + OFF_LU, X, Y);
        vp = eval_poly_lds<16>(sco + OFF_PV, X, Y);
        lv = eval_poly_lds<18>(sco + OFF_LV, X, Y);
    } else {
        // exact whole-wave fallback (never taken for in-distribution inputs)
        up = lu = vp = lv = 0.f;
        for (int jj = 0; jj < UNITS; ++jj) {
            {
                const float dx = x - mu_u[jj], dy = y - mu_u[UNITS + jj];
                const float bb_ = beta_u[jj], ww = W_u[jj];
                const float r2 = fmaf(dx, dx, dy * dy);
                const float ph = expf(-bb_ * r2);
                up = fmaf(ww, ph, up);
                lu = fmaf(ww * ph, fmaf(4.f*bb_*bb_, r2, -4.f*bb_), lu);
            }
            {
                const float dx = x - mu_v[jj], dy = y - mu_v[UNITS + jj];
                const float bb_ = beta_v[jj], ww = W_v[jj];
                const float r2 = fmaf(dx, dx, dy * dy);
                const float ph = expf(-bb_ * r2);
                vp = fmaf(ww, ph, vp);
                lv = fmaf(ww * ph, fmaf(4.f*bb_*bb_, r2, -4.f*bb_), lv);
            }
        }
    }

    // ---- residuals ----
    const float dd = p_d[0],  aa = p_a[0], bb = p_b[0];
    const float um = p_um[0], vm = p_vm[0];
    const float us = p_us[0], vs = p_vs[0];
    const float iu  = 1.0f / us, iv = 1.0f / vs;
    const float cau = (aa - um) * iu;
    const float c4b = 4.0f * bb * iu;
    const float cbv = bb * iv;

    const float uu  = gu[i],  vv  = gv[i];
    const float ddu = gdu[i], ddv = gdv[i];

    float s0, s1, s2, s3, s4, s5;
    {
        float eu = up - uu; s0 = eu * eu;
        float ev = vp - vv; s1 = ev * ev;
        float uph = fmaf(up, us, um);
        float vph = fmaf(vp, vs, vm);
        float den = fmaf(uph, uph, 1.0f);
        float uvd = uph * vph / den;
        float rpu = fmaf(dd, lu, cau) - up - c4b * uvd;
        s2 = rpu * rpu;
        float rdu = lu - ddu; s3 = rdu * rdu;
        float rpv = fmaf(uph, iv, lv) - cbv * uvd;
        s4 = rpv * rpv;
        float rdv = lv - ddv; s5 = rdv * rdv;
    }

    // ---- block reduction (deterministic) ----
    float s[6] = { s0, s1, s2, s3, s4, s5 };
    __shared__ float red[4][6];
    #pragma unroll
    for (int k = 0; k < 6; ++k) {
        float vsum = s[k];
        for (int off = 32; off > 0; off >>= 1)
            vsum += __shfl_down(vsum, off);
        s[k] = vsum;
    }
    const int lane = tid & 63;
    const int wid  = tid >> 6;
    if (lane == 0) {
        #pragma unroll
        for (int k = 0; k < 6; ++k) red[wid][k] = s[k];
    }
    __syncthreads();
    if (tid < 6) {
        float p = red[0][tid] + red[1][tid] + red[2][tid] + red[3][tid];
        part[tid * MBLK + bid] = p;
    }
}

__global__ __launch_bounds__(256) void rbf_final(
    const float* __restrict__ part, float* __restrict__ out)
{
    const int tid = threadIdx.x;
    __shared__ float red[4][6];
    float s[6];
    #pragma unroll
    for (int k = 0; k < 6; ++k) {
        const float* p = part + k * MBLK;
        float vsum = p[tid] + p[tid + 256] + p[tid + 512] + p[tid + 768];
        for (int off = 32; off > 0; off >>= 1)
            vsum += __shfl_down(vsum, off);
        s[k] = vsum;
    }
    const int lane = tid & 63;
    const int wid  = tid >> 6;
    if (lane == 0) {
        #pragma unroll
        for (int k = 0; k < 6; ++k) red[wid][k] = s[k];
    }
    __syncthreads();
    if (tid == 0) {
        const float inv = 1.0f / (float)NPTS;
        const float Lu  = (red[0][0] + red[1][0] + red[2][0] + red[3][0]) * inv;
        const float Lv  = (red[0][1] + red[1][1] + red[2][1] + red[3][1]) * inv;
        const float Lpu = (red[0][2] + red[1][2] + red[2][2] + red[3][2]) * inv;
        const float Ldu = (red[0][3] + red[1][3] + red[2][3] + red[3][3]) * inv;
        const float Lpv = (red[0][4] + red[1][4] + red[2][4] + red[3][4]) * inv;
        const float Ldv = (red[0][5] + red[1][5] + red[2][5] + red[3][5]) * inv;
        out[0] = 0.1f * Lu + 0.1f * Lv + Lpu + Ldu + Lpv + Ldv;
        out[1] = Lu;
        out[2] = Lpu;
        out[3] = Lv;
        out[4] = Lpv;
        out[5] = Ldu;
        out[6] = Ldv;
    }
}

extern "C" void kernel_launch(void* const* d_in, const int* in_sizes, int n_in,
                              void* d_out, int out_size, void* d_ws, size_t ws_size,
                              hipStream_t stream) {
    const float* gx   = (const float*)d_in[0];
    const float* gy   = (const float*)d_in[1];
    const float* gu   = (const float*)d_in[2];
    const float* gv   = (const float*)d_in[3];
    const float* gdu  = (const float*)d_in[4];
    const float* gdv  = (const float*)d_in[5];
    const float* mu_u = (const float*)d_in[6];
    const float* be_u = (const float*)d_in[7];
    const float* W_u  = (const float*)d_in[8];
    const float* mu_v = (const float*)d_in[9];
    const float* be_v = (const float*)d_in[10];
    const float* W_v  = (const float*)d_in[11];
    const float* p_d  = (const float*)d_in[12];
    const float* p_a  = (const float*)d_in[13];
    const float* p_b  = (const float*)d_in[14];
    const float* p_um = (const float*)d_in[15];
    const float* p_vm = (const float*)d_in[16];
    const float* p_us = (const float*)d_in[17];
    const float* p_vs = (const float*)d_in[18];

    float* wsf     = (float*)d_ws;
    float* partial = wsf;                        // 128*1440 = 184320 floats
    float* coefF   = wsf + 184320;               // 1440 floats (16B aligned)
    float* part    = wsf + 185760;               // 6*1024 floats
    int*   flagBlk = (int*)(wsf + 191904);       // 128 ints
    int*   flagAll = (int*)(wsf + 192032);       // 1 int
    float* out     = (float*)d_out;              // 7 floats

    rbf_prep1<<<P1BLK, 256, 0, stream>>>(mu_u, be_u, W_u, mu_v, be_v, W_v,
                                         partial, flagBlk);
    rbf_prep2<<<6, 256, 0, stream>>>(partial, flagBlk, coefF, flagAll);
    rbf_main<<<MBLK, MTPB, 0, stream>>>(gx, gy, gu, gv, gdu, gdv,
                                        coefF, flagAll,
                                        mu_u, be_u, W_u, mu_v, be_v, W_v,
                                        p_d, p_a, p_b, p_um, p_vm, p_us, p_vs,
                                        part);
    rbf_final<<<1, 256, 0, stream>>>(part, out);
}

// Round 9
// 32.704 us; speedup vs baseline: 1.1608x; 1.1608x over previous
//
#include <hip/hip_runtime.h>
#include <hip/hip_bf16.h>
#include <math.h>

#define NPTS   262144
#define UNITS  256
#define STR    19          // rect row stride used inside prep1 power-build
#define NCO    361         // 19*19 rect slots per (j,net) build
#define LSTR   20          // padded output row stride (float4-friendly)
#define OFF_PU 0           // rows 0..16  -> 17*20 = 340
#define OFF_LU 340         // rows 0..18  -> 19*20 = 380
#define OFF_PV 720
#define OFF_LV 1060
#define CFTOT  1440        // total padded coefficient floats
#define P1BLK  128         // prep1 blocks (4 waves each -> 512 (j,net) tasks)
#define PPT    4           // points per thread in main
#define MTPB   256
#define MBLK   256         // MBLK*MTPB*PPT == NPTS ; 1 block/CU
#define QSTRIDE 65536      // point stride between a thread's 4 points

// ---------------------------------------------------------------------------
// prep1: one wave per (unit j, net). Builds the unit's contribution to the
// global bivariate polynomials in centered coords X=x-0.5, Y=y-0.5.
// ---------------------------------------------------------------------------
__global__ __launch_bounds__(256) void rbf_prep1(
    const float* __restrict__ mu_u, const float* __restrict__ beta_u,
    const float* __restrict__ W_u,
    const float* __restrict__ mu_v, const float* __restrict__ beta_v,
    const float* __restrict__ W_v,
    float* __restrict__ partial,   // [P1BLK][CFTOT]
    int* __restrict__ flagBlk)     // [P1BLK]
{
    const int tid  = threadIdx.x;
    const int bid  = blockIdx.x;
    const int w    = tid >> 6;          // wave 0..3
    const int lane = tid & 63;
    const int id   = bid * 4 + w;       // 0..511
    const int j    = id >> 1;
    const int net  = id & 1;

    __shared__ float pwA[4][NCO];
    __shared__ float pwB[4][NCO];
    __shared__ int   sflag[4];

    const float* mu = net ? mu_v   : mu_u;
    const float* be = net ? beta_v : beta_u;
    const float* W  = net ? W_v    : W_u;
    const float mx  = mu[j], my = mu[UNITS + j];
    const float b   = be[j], wgt = W[j];

    // validity of deg-8 approx over safety box [-0.05,1.05]^2
    const float xlo = -0.05f, xhi = 1.05f;
    const float dxl = xlo - mx, dxh = xhi - mx;
    const float dyl = xlo - my, dyh = xhi - my;
    const float dx2max = fmaxf(dxl*dxl, dxh*dxh);
    const float dy2max = fmaxf(dyl*dyl, dyh*dyh);
    const float dx2min = (dxl <= 0.f && dxh >= 0.f) ? 0.f : fminf(dxl*dxl, dxh*dxh);
    const float dy2min = (dyl <= 0.f && dyh >= 0.f) ? 0.f : fminf(dyl*dyl, dyh*dyh);
    const float t1 = b * (dx2min + dy2min);
    const float t2 = b * (dx2max + dy2max);
    const float tlo = fminf(t1, t2), thi = fmaxf(t1, t2);
    const int bad = !(thi <= 2.2f && tlo >= -0.2f);
    if (lane == 0) sflag[w] = bad;

    // quadratic t(X,Y)
    const float ax = mx - 0.5f, ay = my - 0.5f;
    const float qXX = b, qYY = b;
    const float qX = -2.f*b*ax, qY = -2.f*b*ay;
    const float q0 = b*(ax*ax + ay*ay);

    // monomial coeffs of deg-8 Taylor@1 of e^-t
    const float bb[10] = { 0.9999988846f, -0.9999897571f, 0.4999582306f,
                           -0.1665676867f, 0.0415142033f, -0.0081750986f,
                           0.0012773592f, -0.000145983906f, 9.12498118e-06f, 0.f };
    const float fourwb = 4.f * wgt * b;
    float cP[10], cL[10];
    #pragma unroll
    for (int m = 0; m < 10; ++m) {
        cP[m] = wgt * bb[m];
        cL[m] = fourwb * ((m ? bb[m-1] : 0.f) - bb[m]);
    }

    // lane-owned slots c = lane + 64r
    int   cidx[6], gi[6], gm[6];
    float accP[6], accL[6];
    #pragma unroll
    for (int r = 0; r < 6; ++r) {
        const int c = lane + 64*r;
        cidx[r] = c;
        const int ii = c / STR;
        gi[r] = ii;
        gm[r] = c - STR*ii;
        accP[r] = (c == 0) ? cP[0] : 0.f;
        accL[r] = (c == 0) ? cL[0] : 0.f;
        float v = 0.f;
        if (c == 0)     v = q0;
        if (c == 1)     v = qY;
        if (c == 2)     v = qYY;
        if (c == STR)   v = qX;
        if (c == 2*STR) v = qXX;
        if (c < NCO) { pwA[w][c] = v; pwB[w][c] = 0.f; }
    }
    __threadfence_block();

    float* A = &pwA[w][0];
    float* B = &pwB[w][0];
    #pragma unroll
    for (int m = 1; m <= 9; ++m) {
        #pragma unroll
        for (int r = 0; r < 6; ++r) {
            if (cidx[r] < NCO) {
                const float p = A[cidx[r]];
                accP[r] = fmaf(cP[m], p, accP[r]);
                accL[r] = fmaf(cL[m], p, accL[r]);
            }
        }
        if (m < 9) {
            #pragma unroll
            for (int r = 0; r < 6; ++r) {
                const int c = cidx[r];
                if (c < NCO) {
                    float acc = q0 * A[c];
                    if (gm[r] >= 1) acc = fmaf(qY,  A[c-1],     acc);
                    if (gm[r] >= 2) acc = fmaf(qYY, A[c-2],     acc);
                    if (gi[r] >= 1) acc = fmaf(qX,  A[c-STR],   acc);
                    if (gi[r] >= 2) acc = fmaf(qXX, A[c-2*STR], acc);
                    B[c] = acc;
                }
            }
            float* T = A; A = B; B = T;
            __threadfence_block();
        }
    }

    __syncthreads();
    #pragma unroll
    for (int r = 0; r < 6; ++r) {
        const int c = cidx[r];
        if (c < NCO) { pwA[w][c] = accP[r]; pwB[w][c] = accL[r]; }
    }
    __syncthreads();
    // write ALL 361 rect slots into the padded stride-20 output layout
    {
        float* dst = partial + bid * CFTOT;
        for (int c = tid; c < NCO; c += 256) {
            const int i = c / STR;
            const int m = c - STR * i;
            const float pu = pwA[0][c] + pwA[2][c];
            const float lu = pwB[0][c] + pwB[2][c];
            const float pv = pwA[1][c] + pwA[3][c];
            const float lv = pwB[1][c] + pwB[3][c];
            if (i <= 16) {
                dst[OFF_PU + i*LSTR + m] = pu;
                dst[OFF_PV + i*LSTR + m] = pv;
            }
            dst[OFF_LU + i*LSTR + m] = lu;
            dst[OFF_LV + i*LSTR + m] = lv;
        }
    }
    if (tid == 0)
        flagBlk[bid] = sflag[0] | sflag[1] | sflag[2] | sflag[3];
}

// ---------------------------------------------------------------------------
// prep2: fold 128 block-partials into the final coefficient table + flag.
// ---------------------------------------------------------------------------
__global__ __launch_bounds__(256) void rbf_prep2(
    const float* __restrict__ partial, const int* __restrict__ flagBlk,
    float* __restrict__ coefF, int* __restrict__ flagAll)
{
    const int c = blockIdx.x * 256 + threadIdx.x;
    if (c < CFTOT) {
        float s = 0.f;
        #pragma unroll 8
        for (int p = 0; p < P1BLK; ++p)
            s += partial[p * CFTOT + c];
        coefF[c] = s;
    }
    if (c == CFTOT) {
        int f = 0;
        for (int p = 0; p < P1BLK; ++p) f |= flagBlk[p];
        *flagAll = f;
    }
}

// ---------------------------------------------------------------------------
// eval4: evaluate one padded (stride-20) bivariate poly of total degree D at
// 4 points simultaneously. Reads coefficients as float4 from LDS (one
// ds_read_b128 feeds 16 FMAs). Horner in Y within rows, Horner in X across.
// Trimmed to the needed quads per row; pad slots hold ~1e-11 dust (harmless).
// ---------------------------------------------------------------------------
template<int D>
__device__ __forceinline__ void eval4(const float* sco,
    float X0, float X1, float X2, float X3,
    float Y0, float Y1, float Y2, float Y3,
    float& h0, float& h1, float& h2, float& h3)
{
    h0 = h1 = h2 = h3 = 0.f;
    #pragma unroll
    for (int ii = 0; ii <= D; ++ii) {
        const int i = D - ii;                 // row, from high X-degree down
        const int K = (D - i + 4) / 4;        // quads needed in this row
        float r0 = 0.f, r1 = 0.f, r2 = 0.f, r3 = 0.f;
        #pragma unroll
        for (int kk = 0; kk < K; ++kk) {
            const int k = K - 1 - kk;
            const float4 q = *(const float4*)(sco + i*LSTR + 4*k);
            r0 = fmaf(r0, Y0, q.w); r1 = fmaf(r1, Y1, q.w);
            r2 = fmaf(r2, Y2, q.w); r3 = fmaf(r3, Y3, q.w);
            r0 = fmaf(r0, Y0, q.z); r1 = fmaf(r1, Y1, q.z);
            r2 = fmaf(r2, Y2, q.z); r3 = fmaf(r3, Y3, q.z);
            r0 = fmaf(r0, Y0, q.y); r1 = fmaf(r1, Y1, q.y);
            r2 = fmaf(r2, Y2, q.y); r3 = fmaf(r3, Y3, q.y);
            r0 = fmaf(r0, Y0, q.x); r1 = fmaf(r1, Y1, q.x);
            r2 = fmaf(r2, Y2, q.x); r3 = fmaf(r3, Y3, q.x);
        }
        h0 = fmaf(h0, X0, r0); h1 = fmaf(h1, X1, r1);
        h2 = fmaf(h2, X2, r2); h3 = fmaf(h3, X3, r3);
    }
}

__global__ __launch_bounds__(MTPB) void rbf_main(
    const float* __restrict__ gx, const float* __restrict__ gy,
    const float* __restrict__ gu, const float* __restrict__ gv,
    const float* __restrict__ gdu, const float* __restrict__ gdv,
    const float* __restrict__ coefF, const int* __restrict__ flagAll,
    const float* __restrict__ mu_u, const float* __restrict__ beta_u,
    const float* __restrict__ W_u,
    const float* __restrict__ mu_v, const float* __restrict__ beta_v,
    const float* __restrict__ W_v,
    const float* __restrict__ p_d, const float* __restrict__ p_a,
    const float* __restrict__ p_b, const float* __restrict__ p_um,
    const float* __restrict__ p_vm, const float* __restrict__ p_us,
    const float* __restrict__ p_vs,
    float* __restrict__ part)
{
    const int tid = threadIdx.x;
    const int bid = blockIdx.x;
    const int i0  = bid * MTPB + tid;

    __shared__ __align__(16) float sco[CFTOT];   // 5.76 KB coef table
    {
        const float4* src4 = (const float4*)coefF;
        float4* dst4 = (float4*)sco;
        #pragma unroll
        for (int k = 0; k < CFTOT/4/MTPB + 1; ++k) {
            const int idx = k * MTPB + tid;
            if (idx < CFTOT/4) dst4[idx] = src4[idx];
        }
    }
    __syncthreads();

    float xs[PPT], ys[PPT];
    #pragma unroll
    for (int p = 0; p < PPT; ++p) {
        xs[p] = gx[i0 + p*QSTRIDE];
        ys[p] = gy[i0 + p*QSTRIDE];
    }

    const int bad = __builtin_amdgcn_readfirstlane(*flagAll);
    bool in = true;
    #pragma unroll
    for (int p = 0; p < PPT; ++p)
        in = in && (xs[p] >= -0.05f) && (xs[p] <= 1.05f)
                && (ys[p] >= -0.05f) && (ys[p] <= 1.05f);
    const bool allIn = __all(in);

    float up[PPT], vp[PPT], lu[PPT], lv[PPT];
    if (!bad && allIn) {
        const float X0 = xs[0]-0.5f, X1 = xs[1]-0.5f, X2 = xs[2]-0.5f, X3 = xs[3]-0.5f;
        const float Y0 = ys[0]-0.5f, Y1 = ys[1]-0.5f, Y2 = ys[2]-0.5f, Y3 = ys[3]-0.5f;
        eval4<16>(sco + OFF_PU, X0,X1,X2,X3, Y0,Y1,Y2,Y3, up[0],up[1],up[2],up[3]);
        eval4<18>(sco + OFF_LU, X0,X1,X2,X3, Y0,Y1,Y2,Y3, lu[0],lu[1],lu[2],lu[3]);
        eval4<16>(sco + OFF_PV, X0,X1,X2,X3, Y0,Y1,Y2,Y3, vp[0],vp[1],vp[2],vp[3]);
        eval4<18>(sco + OFF_LV, X0,X1,X2,X3, Y0,Y1,Y2,Y3, lv[0],lv[1],lv[2],lv[3]);
    } else {
        // exact whole-wave fallback (never taken for in-distribution inputs)
        #pragma unroll
        for (int p = 0; p < PPT; ++p) { up[p]=lu[p]=vp[p]=lv[p]=0.f; }
        for (int jj = 0; jj < UNITS; ++jj) {
            const float mxu = mu_u[jj], myu = mu_u[UNITS + jj];
            const float bu_ = beta_u[jj], wu_ = W_u[jj];
            const float mxv = mu_v[jj], myv = mu_v[UNITS + jj];
            const float bv_ = beta_v[jj], wv_ = W_v[jj];
            #pragma unroll
            for (int p = 0; p < PPT; ++p) {
                {
                    const float dx = xs[p] - mxu, dy = ys[p] - myu;
                    const float r2 = fmaf(dx, dx, dy * dy);
                    const float ph = expf(-bu_ * r2);
                    up[p] = fmaf(wu_, ph, up[p]);
                    lu[p] = fmaf(wu_ * ph, fmaf(4.f*bu_*bu_, r2, -4.f*bu_), lu[p]);
                }
                {
                    const float dx = xs[p] - mxv, dy = ys[p] - myv;
                    const float r2 = fmaf(dx, dx, dy * dy);
                    const float ph = expf(-bv_ * r2);
                    vp[p] = fmaf(wv_, ph, vp[p]);
                    lv[p] = fmaf(wv_ * ph, fmaf(4.f*bv_*bv_, r2, -4.f*bv_), lv[p]);
                }
            }
        }
    }

    // ---- residuals ----
    const float dd = p_d[0],  aa = p_a[0], bb = p_b[0];
    const float um = p_um[0], vm = p_vm[0];
    const float us = p_us[0], vs = p_vs[0];
    const float iu  = 1.0f / us, iv = 1.0f / vs;
    const float cau = (aa - um) * iu;
    const float c4b = 4.0f * bb * iu;
    const float cbv = bb * iv;

    float s0 = 0.f, s1 = 0.f, s2 = 0.f, s3 = 0.f, s4 = 0.f, s5 = 0.f;
    #pragma unroll
    for (int p = 0; p < PPT; ++p) {
        const int ii = i0 + p*QSTRIDE;
        const float uu  = gu[ii],  vv  = gv[ii];
        const float ddu = gdu[ii], ddv = gdv[ii];
        float eu = up[p] - uu; s0 += eu * eu;
        float ev = vp[p] - vv; s1 += ev * ev;
        float uph = fmaf(up[p], us, um);
        float vph = fmaf(vp[p], vs, vm);
        float den = fmaf(uph, uph, 1.0f);
        float uvd = uph * vph / den;
        float rpu = fmaf(dd, lu[p], cau) - up[p] - c4b * uvd;
        s2 += rpu * rpu;
        float rdu = lu[p] - ddu; s3 += rdu * rdu;
        float rpv = fmaf(uph, iv, lv[p]) - cbv * uvd;
        s4 += rpv * rpv;
        float rdv = lv[p] - ddv; s5 += rdv * rdv;
    }

    // ---- block reduction (deterministic) ----
    float s[6] = { s0, s1, s2, s3, s4, s5 };
    __shared__ float red[4][6];
    #pragma unroll
    for (int k = 0; k < 6; ++k) {
        float vsum = s[k];
        for (int off = 32; off > 0; off >>= 1)
            vsum += __shfl_down(vsum, off);
        s[k] = vsum;
    }
    const int lane = tid & 63;
    const int wid  = tid >> 6;
    if (lane == 0) {
        #pragma unroll
        for (int k = 0; k < 6; ++k) red[wid][k] = s[k];
    }
    __syncthreads();
    if (tid < 6) {
        float p = red[0][tid] + red[1][tid] + red[2][tid] + red[3][tid];
        part[tid * MBLK + bid] = p;
    }
}

__global__ __launch_bounds__(256) void rbf_final(
    const float* __restrict__ part, float* __restrict__ out)
{
    const int tid = threadIdx.x;
    __shared__ float red[4][6];
    float s[6];
    #pragma unroll
    for (int k = 0; k < 6; ++k) {
        float vsum = part[k * MBLK + tid];
        for (int off = 32; off > 0; off >>= 1)
            vsum += __shfl_down(vsum, off);
        s[k] = vsum;
    }
    const int lane = tid & 63;
    const int wid  = tid >> 6;
    if (lane == 0) {
        #pragma unroll
        for (int k = 0; k < 6; ++k) red[wid][k] = s[k];
    }
    __syncthreads();
    if (tid == 0) {
        const float inv = 1.0f / (float)NPTS;
        const float Lu  = (red[0][0] + red[1][0] + red[2][0] + red[3][0]) * inv;
        const float Lv  = (red[0][1] + red[1][1] + red[2][1] + red[3][1]) * inv;
        const float Lpu = (red[0][2] + red[1][2] + red[2][2] + red[3][2]) * inv;
        const float Ldu = (red[0][3] + red[1][3] + red[2][3] + red[3][3]) * inv;
        const float Lpv = (red[0][4] + red[1][4] + red[2][4] + red[3][4]) * inv;
        const float Ldv = (red[0][5] + red[1][5] + red[2][5] + red[3][5]) * inv;
        out[0] = 0.1f * Lu + 0.1f * Lv + Lpu + Ldu + Lpv + Ldv;
        out[1] = Lu;
        out[2] = Lpu;
        out[3] = Lv;
        out[4] = Lpv;
        out[5] = Ldu;
        out[6] = Ldv;
    }
}

extern "C" void kernel_launch(void* const* d_in, const int* in_sizes, int n_in,
                              void* d_out, int out_size, void* d_ws, size_t ws_size,
                              hipStream_t stream) {
    const float* gx   = (const float*)d_in[0];
    const float* gy   = (const float*)d_in[1];
    const float* gu   = (const float*)d_in[2];
    const float* gv   = (const float*)d_in[3];
    const float* gdu  = (const float*)d_in[4];
    const float* gdv  = (const float*)d_in[5];
    const float* mu_u = (const float*)d_in[6];
    const float* be_u = (const float*)d_in[7];
    const float* W_u  = (const float*)d_in[8];
    const float* mu_v = (const float*)d_in[9];
    const float* be_v = (const float*)d_in[10];
    const float* W_v  = (const float*)d_in[11];
    const float* p_d  = (const float*)d_in[12];
    const float* p_a  = (const float*)d_in[13];
    const float* p_b  = (const float*)d_in[14];
    const float* p_um = (const float*)d_in[15];
    const float* p_vm = (const float*)d_in[16];
    const float* p_us = (const float*)d_in[17];
    const float* p_vs = (const float*)d_in[18];

    float* wsf     = (float*)d_ws;
    float* partial = wsf;                        // 128*1440 = 184320 floats
    float* coefF   = wsf + 184320;               // 1440 floats (16B aligned)
    float* part    = wsf + 185760;               // 6*256 floats
    int*   flagBlk = (int*)(wsf + 187296);       // 128 ints
    int*   flagAll = (int*)(wsf + 187424);       // 1 int
    float* out     = (float*)d_out;              // 7 floats

    rbf_prep1<<<P1BLK, 256, 0, stream>>>(mu_u, be_u, W_u, mu_v, be_v, W_v,
                                         partial, flagBlk);
    rbf_prep2<<<6, 256, 0, stream>>>(partial, flagBlk, coefF, flagAll);
    rbf_main<<<MBLK, MTPB, 0, stream>>>(gx, gy, gu, gv, gdu, gdv,
                                        coefF, flagAll,
                                        mu_u, be_u, W_u, mu_v, be_v, W_v,
                                        p_d, p_a, p_b, p_um, p_vm, p_us, p_vs,
                                        part);
    rbf_final<<<1, 256, 0, stream>>>(part, out);
}